// Round 15
// baseline (608.574 us; speedup 1.0000x reference)
//
#include <hip/hip_runtime.h>
#include <cmath>

// CrossKDDenseNet fused block for MI355X (gfx950).
// B=32768 rows, D=688 = 4 heads x 172, MLP hidden 128.
// Round 15: r14 base + fp8 qkv tensor with FIXED attn load path
// (dword loads + hw v_cvt_pk_f32_fp8 decode; r13's failure was scalar
// byte loads, not fp8). QKV writes halve; attn reads halve.

#define B_ROWS 32768
#define D_DIM  688
#define DP     704     // padded K / activation stride (fp8 bytes; 11 x 64)
#define DH_DIM 172
#define MH_DIM 128

typedef unsigned short ushort_t;
typedef unsigned char  u8;
typedef __attribute__((ext_vector_type(8))) __bf16 bf16x8;
typedef __attribute__((ext_vector_type(4))) float  f32x4;

__device__ __forceinline__ float b2f(ushort_t u) {
    return __builtin_bit_cast(float, (unsigned int)u << 16);
}
__device__ __forceinline__ ushort_t f2bf(float f) {
    unsigned int u = __builtin_bit_cast(unsigned int, f);
    u += 0x7FFFu + ((u >> 16) & 1u);   // round-to-nearest-even (finite inputs)
    return (ushort_t)(u >> 16);
}
__device__ __forceinline__ unsigned int pk4fp8(float a, float b, float c, float d) {
    int v = 0;
    v = __builtin_amdgcn_cvt_pk_fp8_f32(a, b, v, false);   // low word
    v = __builtin_amdgcn_cvt_pk_fp8_f32(c, d, v, true);    // high word
    return (unsigned int)v;
}
__device__ __forceinline__ u8 f2fp8(float a) {
    return (u8)(__builtin_amdgcn_cvt_pk_fp8_f32(a, 0.f, 0, false) & 0xff);
}
// branchless e4m3fn -> f32 fallback (values here never hit NaN encoding)
__device__ __forceinline__ float fp82f_sw(u8 b) {
    const unsigned s = ((unsigned)b & 0x80u) << 24;
    const unsigned e = ((unsigned)b >> 3) & 15u;
    const unsigned m = (unsigned)b & 7u;
    float mag = e ? __builtin_bit_cast(float, ((e + 120u) << 23) | (m << 20))
                  : (float)m * 0.001953125f;   // 2^-9
    return __builtin_bit_cast(float, __builtin_bit_cast(unsigned, mag) | s);
}
// decode 4 packed fp8 (one dword) -> 4 floats
__device__ __forceinline__ void dec4fp8(unsigned int w, float* o) {
#if __has_builtin(__builtin_amdgcn_cvt_pk_f32_fp8)
    auto lo = __builtin_amdgcn_cvt_pk_f32_fp8((int)w, false);
    auto hi = __builtin_amdgcn_cvt_pk_f32_fp8((int)w, true);
    o[0] = lo[0]; o[1] = lo[1]; o[2] = hi[0]; o[3] = hi[1];
#else
    o[0] = fp82f_sw((u8)(w));
    o[1] = fp82f_sw((u8)(w >> 8));
    o[2] = fp82f_sw((u8)(w >> 16));
    o[3] = fp82f_sw((u8)(w >> 24));
#endif
}

__device__ __forceinline__ void gl2lds16(const void* g, void* l) {
    __builtin_amdgcn_global_load_lds(
        (const __attribute__((address_space(1))) unsigned int*)g,
        (__attribute__((address_space(3))) unsigned int*)l, 16, 0, 0);
}

// ---------------- merged weight convert (fp8 or bf16) with zero padding ----------
struct CvtJobs {
    const float* src[12];
    u8*          dst[12];
    int O[12], Opad[12], Kin[12], KpadB[12];   // KpadB = padded row bytes
    int isfp8[12];
    int bstart[13];
};

__global__ __launch_bounds__(256)
void cvt_all(CvtJobs jobs)
{
    int b = blockIdx.x;
    int j = 0;
    while (b >= jobs.bstart[j + 1]) ++j;
    const int t = (b - jobs.bstart[j]) * 256 + threadIdx.x;
    const int KpadB = jobs.KpadB[j];
    const int Kin   = jobs.Kin[j];
    const int cpr   = KpadB >> 4;              // 16B chunks per dst row
    if (t >= jobs.Opad[j] * cpr) return;
    const int o = t / cpr;
    const int c = t - o * cpr;
    uint4 out = make_uint4(0, 0, 0, 0);
    if (jobs.isfp8[j]) {                       // 16 fp8 per chunk
        if (o < jobs.O[j] && (c * 16 + 16) <= Kin) {
            const float4* s = reinterpret_cast<const float4*>(jobs.src[j] + (size_t)o * Kin + c * 16);
            float4 f0 = s[0], f1 = s[1], f2 = s[2], f3 = s[3];
            out.x = pk4fp8(f0.x, f0.y, f0.z, f0.w);
            out.y = pk4fp8(f1.x, f1.y, f1.z, f1.w);
            out.z = pk4fp8(f2.x, f2.y, f2.z, f2.w);
            out.w = pk4fp8(f3.x, f3.y, f3.z, f3.w);
        }
    } else {                                   // 8 bf16 per chunk
        if (o < jobs.O[j] && (c * 8 + 8) <= Kin) {
            const float4* s = reinterpret_cast<const float4*>(jobs.src[j] + (size_t)o * Kin + c * 8);
            float4 f0 = s[0], f1 = s[1];
            out.x = f2bf(f0.x) | ((unsigned int)f2bf(f0.y) << 16);
            out.y = f2bf(f0.z) | ((unsigned int)f2bf(f0.w) << 16);
            out.z = f2bf(f1.x) | ((unsigned int)f2bf(f1.y) << 16);
            out.w = f2bf(f1.z) | ((unsigned int)f2bf(f1.w) << 16);
        }
    }
    *reinterpret_cast<uint4*>(jobs.dst[j] + (size_t)o * KpadB + c * 16) = out;
}

// ---------------- concat 3 biases per stream ----------------
__global__ __launch_bounds__(256)
void pack_bias(const float* __restrict__ a0, const float* __restrict__ a1,
               const float* __restrict__ a2, const float* __restrict__ b0,
               const float* __restrict__ b1, const float* __restrict__ b2,
               float* __restrict__ dv, float* __restrict__ di)
{
    int t = blockIdx.x * 256 + threadIdx.x;
    if (t >= 2064) return;
    float v, w;
    if (t < 688)       { v = a0[t];        w = b0[t]; }
    else if (t < 1376) { v = a1[t - 688];  w = b1[t - 688]; }
    else               { v = a2[t - 1376]; w = b2[t - 1376]; }
    dv[t] = v; di[t] = w;
}

// ---------------- LayerNorm fp32-in -> fp8 out; stride DP bytes, pad zeroed -----
__global__ __launch_bounds__(256)
void ln_kernel(const float* __restrict__ Xv, const float* __restrict__ Xi,
               const float* __restrict__ gv, const float* __restrict__ bv,
               const float* __restrict__ gi, const float* __restrict__ bi,
               u8* __restrict__ Yv, u8* __restrict__ Yi)
{
    const int lane = threadIdx.x & 63;
    const int wave = threadIdx.x >> 6;
    const long w = (long)blockIdx.x * 4 + wave;   // 0 .. 2B-1
    const float* X; const float* g; const float* b; u8* Y; long r;
    if (w < B_ROWS) { X = Xv; g = gv; b = bv; Y = Yv; r = w; }
    else            { X = Xi; g = gi; b = bi; Y = Yi; r = w - B_ROWS; }

    const float4* row = reinterpret_cast<const float4*>(X + r * D_DIM);
    float4 v0 = row[lane];
    float4 v1 = row[lane + 64];
    float4 v2 = make_float4(0.f, 0.f, 0.f, 0.f);
    if (lane < 44) v2 = row[lane + 128];   // 172 float4 per row

    float s  = v0.x + v0.y + v0.z + v0.w + v1.x + v1.y + v1.z + v1.w
             + v2.x + v2.y + v2.z + v2.w;
    float s2 = v0.x*v0.x + v0.y*v0.y + v0.z*v0.z + v0.w*v0.w
             + v1.x*v1.x + v1.y*v1.y + v1.z*v1.z + v1.w*v1.w
             + v2.x*v2.x + v2.y*v2.y + v2.z*v2.z + v2.w*v2.w;
#pragma unroll
    for (int m = 32; m; m >>= 1) { s += __shfl_xor(s, m); s2 += __shfl_xor(s2, m); }

    const float mean = s * (1.f / 688.f);
    const float var  = s2 * (1.f / 688.f) - mean * mean;   // biased var
    const float rstd = rsqrtf(var + 1e-5f);

    const float4* g4 = reinterpret_cast<const float4*>(g);
    const float4* b4 = reinterpret_cast<const float4*>(b);
    unsigned int* out32 = reinterpret_cast<unsigned int*>(Y + (size_t)r * DP);

    {
        float4 gg = g4[lane], bb = b4[lane];
        out32[lane] = pk4fp8((v0.x - mean) * rstd * gg.x + bb.x,
                             (v0.y - mean) * rstd * gg.y + bb.y,
                             (v0.z - mean) * rstd * gg.z + bb.z,
                             (v0.w - mean) * rstd * gg.w + bb.w);
    }
    {
        float4 gg = g4[lane + 64], bb = b4[lane + 64];
        out32[lane + 64] = pk4fp8((v1.x - mean) * rstd * gg.x + bb.x,
                                  (v1.y - mean) * rstd * gg.y + bb.y,
                                  (v1.z - mean) * rstd * gg.z + bb.z,
                                  (v1.w - mean) * rstd * gg.w + bb.w);
    }
    if (lane < 44) {
        float4 gg = g4[lane + 128], bb = b4[lane + 128];
        out32[lane + 128] = pk4fp8((v2.x - mean) * rstd * gg.x + bb.x,
                                   (v2.y - mean) * rstd * gg.y + bb.y,
                                   (v2.z - mean) * rstd * gg.z + bb.z,
                                   (v2.w - mean) * rstd * gg.w + bb.w);
    } else if (lane < 48) {
        out32[lane + 128] = 0u;            // zero K-pad 688..703
    }
}

// ================= gemmT (fp8): 256x128 tile, 4 waves x (128x64), BK=64 ========
// C(M,N) = A(M,K) @ W(N',K)^T with fp8 e4m3 operands, K=704 (11 K-tiles of 64).
// Triple-buffered 72 KB LDS (buf: A 16KB | B 8KB), one barrier per tile:
// {STAGE(t+2) | vmcnt(6) | lgkmcnt(0) | bar | 64 MFMA(t) | RD(t+1)}.
// b64 fragment reads (round-12/14 proven pattern).
// MODE 0: out fp8 = v + bias             MODE 1: out bf16 = cA*res_f32 + cB*(v+bias)
template<int MODE>
__global__ __launch_bounds__(256, 2)
void gemmT(const u8* __restrict__ A0, const u8* __restrict__ A1,
           const u8* __restrict__ W0, const u8* __restrict__ W1,
           const float* __restrict__ bias0, const float* __restrict__ bias1,
           void* __restrict__ out0, void* __restrict__ out1,
           const float* __restrict__ res0, const float* __restrict__ res1,
           const float* __restrict__ coef, int ca0, int cb0, int ca1, int cb1,
           int NBn, int N, int K, int lda, int ldw, int ldo)
{
    __shared__ __align__(16) u8 lds[73728];   // 3 bufs x 24576 B

    // bijective XCD swizzle (grid%8==0), n fastest (A-strip L2 reuse)
    const int q8 = gridDim.x >> 3;
    const int v  = (blockIdx.x & 7) * q8 + (blockIdx.x >> 3);
    const int nb = v % NBn;
    const int tmp = v / NBn;
    const int mb = tmp & 127;          // M/256 == 128
    const int zz = tmp >> 7;

    const u8* A = zz ? A1 : A0;
    const u8* W = zz ? W1 : W0;
    const float* bias = zz ? bias1 : bias0;
    void* outp        = zz ? out1 : out0;
    const float* resid = zz ? res1 : res0;
    const int ca = zz ? ca1 : ca0;
    const int cb = zz ? cb1 : cb0;

    const int tid  = threadIdx.x;
    const int lane = tid & 63;
    const int wave = tid >> 6;          // 0..3
    const int wrow = wave >> 1;         // 0..1  (128-row band)
    const int wcol = wave & 1;          // 0..1  (64-col band)
    const int m0 = mb * 256;
    const int n0 = nb * 128;
    const int rl16 = lane & 15;
    const int q4   = lane >> 4;

    const int r0a  = (wave * 64 + lane) >> 2;               // 0..63
    const int swzk = ((lane & 3) ^ ((lane >> 3) & 3)) * 16; // pre-swizzled byte col

    f32x4 acc[8][4];
#pragma unroll
    for (int i = 0; i < 8; ++i)
#pragma unroll
        for (int j = 0; j < 4; ++j)
            acc[i][j] = f32x4{0.f, 0.f, 0.f, 0.f};

    const int NT = K >> 6;              // 11

#define STAGET(kt, bb) do {                                                        \
    const u8* _a = A + (size_t)(m0 + r0a) * lda + (kt)*64 + swzk;                  \
    gl2lds16(_a,                     lds + (bb)*24576 + wave*1024);                \
    gl2lds16(_a +  64*(size_t)lda,   lds + (bb)*24576 + 4096 + wave*1024);         \
    gl2lds16(_a + 128*(size_t)lda,   lds + (bb)*24576 + 8192 + wave*1024);         \
    gl2lds16(_a + 192*(size_t)lda,   lds + (bb)*24576 + 12288 + wave*1024);        \
    const u8* _b = W + (size_t)(n0 + r0a) * ldw + (kt)*64 + swzk;                  \
    gl2lds16(_b,                     lds + (bb)*24576 + 16384 + wave*1024);        \
    gl2lds16(_b +  64*(size_t)ldw,   lds + (bb)*24576 + 20480 + wave*1024);        \
} while (0)

#define RDFRAG(bb) do {                                                            \
    _Pragma("unroll")                                                              \
    for (int kk = 0; kk < 2; ++kk) {                                               \
        const int bo = kk * 32 + q4 * 8;                                           \
        const int ch = bo >> 4, sb = bo & 15;                                      \
        _Pragma("unroll")                                                          \
        for (int i = 0; i < 8; ++i) {                                              \
            const int row_ = wrow * 128 + i * 16 + rl16;                           \
            af[kk][i] = *reinterpret_cast<const long*>(                            \
                lds + (bb) * 24576 + row_ * 64 + (((ch ^ ((row_ >> 1) & 3)) << 4) | sb)); \
        }                                                                          \
        _Pragma("unroll")                                                          \
        for (int j = 0; j < 4; ++j) {                                              \
            const int row_ = wcol * 64 + j * 16 + rl16;                            \
            bw[kk][j] = *reinterpret_cast<const long*>(                            \
                lds + (bb) * 24576 + 16384 + row_ * 64 + (((ch ^ ((row_ >> 1) & 3)) << 4) | sb)); \
        }                                                                          \
    } } while (0)

    long af[2][8], bw[2][4];

    // ---- prologue: tiles 0 and 1 in flight; read tile-0 fragments ----
    STAGET(0, 0);
    STAGET(1, 1);
    asm volatile("s_waitcnt vmcnt(6)" ::: "memory");   // tile 0 landed (own)
    __builtin_amdgcn_s_barrier();                      // all waves' tile 0 landed
    RDFRAG(0);

    for (int t = 0; t < NT; ++t) {
        const int tn2 = (t + 2 < NT) ? t + 2 : NT - 1; // clamped tail (dead bufs)
        STAGET(tn2, (t + 2) % 3);
        asm volatile("s_waitcnt vmcnt(6)" ::: "memory");    // tile t+1 landed (own)
        asm volatile("s_waitcnt lgkmcnt(0)" ::: "memory");  // my RD(t) complete
        __builtin_amdgcn_s_barrier();   // all waves: t+1 landed AND RD(t) drained
        __builtin_amdgcn_s_setprio(1);
#pragma unroll
        for (int kk = 0; kk < 2; ++kk)
#pragma unroll
            for (int i = 0; i < 8; ++i)
#pragma unroll
                for (int j = 0; j < 4; ++j)
                    acc[i][j] = __builtin_amdgcn_mfma_f32_16x16x32_fp8_fp8(
                        af[kk][i], bw[kk][j], acc[i][j], 0, 0, 0);
        __builtin_amdgcn_s_setprio(0);
        if (t + 1 < NT) RDFRAG((t + 1) % 3);   // next tile's frags
    }

    // ---- epilogue: drain all, repack C (256x128 bf16) through LDS, wide stores -
    __syncthreads();   // vmcnt(0) + lgkmcnt(0) + barrier

    ushort_t* const Cl = reinterpret_cast<ushort_t*>(lds);   // [256][128] bf16 = 64 KB
#pragma unroll
    for (int mi = 0; mi < 8; ++mi)
#pragma unroll
        for (int nj = 0; nj < 4; ++nj)
#pragma unroll
            for (int r = 0; r < 4; ++r) {
                const int row  = wrow * 128 + mi * 16 + q4 * 4 + r;
                const int colL = wcol * 64 + nj * 16 + rl16;
                const int blk  = (colL >> 3) ^ (((row >> 2) & 3) << 1);
                Cl[row * 128 + blk * 8 + (colL & 7)] = f2bf(acc[mi][nj][r]);
            }
    __syncthreads();

    float cA = 0.f, cB = 1.f;
    if constexpr (MODE == 1) { cA = coef[ca]; cB = coef[cb]; }
#pragma unroll
    for (int it2 = 0; it2 < 16; ++it2) {
        const int c   = it2 * 256 + tid;   // 4096 chunks of 8 elems
        const int row = c >> 4;
        const int lb  = c & 15;
        const int gcol = n0 + lb * 8;
        if (gcol >= N) continue;        // N % 8 == 0
        const int pb = lb ^ (((row >> 2) & 3) << 1);
        uint4 pv = *reinterpret_cast<const uint4*>(Cl + row * 128 + pb * 8);
        const ushort_t* pu = (const ushort_t*)&pv;
        float4 b0 = *reinterpret_cast<const float4*>(bias + gcol);
        float4 b1 = *reinterpret_cast<const float4*>(bias + gcol + 4);
        const float bb[8] = {b0.x, b0.y, b0.z, b0.w, b1.x, b1.y, b1.z, b1.w};
        const size_t idx = (size_t)(m0 + row) * ldo + gcol;
        if constexpr (MODE == 0) {          // fp8 out (qkv)
            float vv[8];
#pragma unroll
            for (int k = 0; k < 8; ++k) vv[k] = b2f(pu[k]) + bb[k];
            uint2 o;
            o.x = pk4fp8(vv[0], vv[1], vv[2], vv[3]);
            o.y = pk4fp8(vv[4], vv[5], vv[6], vv[7]);
            *reinterpret_cast<uint2*>((u8*)outp + idx) = o;
        } else {                            // bf16 out + fp32 resid
            const float* rp = resid + idx;
            float4 r0_ = reinterpret_cast<const float4*>(rp)[0];
            float4 r1_ = reinterpret_cast<const float4*>(rp)[1];
            const float rr[8] = {r0_.x, r0_.y, r0_.z, r0_.w, r1_.x, r1_.y, r1_.z, r1_.w};
            ushort_t o[8];
#pragma unroll
            for (int k = 0; k < 8; ++k)
                o[k] = f2bf(cA * rr[k] + cB * (b2f(pu[k]) + bb[k]));
            *reinterpret_cast<uint4*>((ushort_t*)outp + idx) = *reinterpret_cast<uint4*>(o);
        }
    }
#undef STAGET
#undef RDFRAG
}

// ---------------- fused LN3/4 + MLP1 + gelu + MLP2 + final residual ------------
// Block = 32 rows of one stream (LDS ~60 KB -> 2 blocks/CU). bf16 path.
__global__ __launch_bounds__(256)
void mlp_fused(const ushort_t* __restrict__ ov0, const ushort_t* __restrict__ ov1,
               const float* __restrict__ g0, const float* __restrict__ b0,
               const float* __restrict__ g1, const float* __restrict__ b1,
               const ushort_t* __restrict__ W10, const ushort_t* __restrict__ W11,
               const float* __restrict__ mb10, const float* __restrict__ mb11,
               const ushort_t* __restrict__ W20, const ushort_t* __restrict__ W21,
               const float* __restrict__ mb20, const float* __restrict__ mb21,
               const float* __restrict__ coef,
               float* __restrict__ out0, float* __restrict__ out1)
{
    __shared__ __align__(16) ushort_t hraw[32 * 712];   // 45.6 KB
    __shared__ __align__(16) ushort_t gbuf[32 * 136];   // 8.7 KB
    __shared__ float glds[704];
    __shared__ float blds[704];
    __shared__ float mlds[32];
    __shared__ float rlds[32];

    const int zz = blockIdx.y;
    const ushort_t* ovb = zz ? ov1 : ov0;
    const float* lg = zz ? g1 : g0;
    const float* lb = zz ? b1 : b0;
    const ushort_t* W1 = zz ? W11 : W10;
    const float* mb1 = zz ? mb11 : mb10;
    const ushort_t* W2 = zz ? W21 : W20;
    const float* mb2 = zz ? mb21 : mb20;
    float* outp = zz ? out1 : out0;
    const float cA = coef[zz ? 6 : 4];
    const float cB = coef[zz ? 7 : 5];

    const int tid  = threadIdx.x;
    const int lane = tid & 63;
    const int wv   = tid >> 6;          // 0..3
    const long r0  = (long)blockIdx.x * 32;

    if (tid < 176) {
        float4 gg = make_float4(0, 0, 0, 0), bb = make_float4(0, 0, 0, 0);
        if (tid < 172) {
            gg = reinterpret_cast<const float4*>(lg)[tid];
            bb = reinterpret_cast<const float4*>(lb)[tid];
        }
        reinterpret_cast<float4*>(glds)[tid] = gg;
        reinterpret_cast<float4*>(blds)[tid] = bb;
    }

    // phase 1: raw rows -> LDS; cols 688..703 zeroed
#pragma unroll
    for (int it = 0; it < 11; ++it) {
        const int c = it * 256 + tid;
        const int row = c / 88;
        const int u = c - row * 88;
        uint4 vv = make_uint4(0, 0, 0, 0);
        if (u < 86)
            vv = *reinterpret_cast<const uint4*>(ovb + (r0 + row) * 688 + u * 8);
        *reinterpret_cast<uint4*>(&hraw[row * 712 + u * 8]) = vv;
    }
    __syncthreads();

    // phase 2: per-row stats
    for (int rr = 0; rr < 8; ++rr) {
        const int row = wv * 8 + rr;
        const ushort_t* hp = &hraw[row * 712];
        ushort4 a0 = *reinterpret_cast<const ushort4*>(hp + lane * 4);
        ushort4 a1 = *reinterpret_cast<const ushort4*>(hp + 256 + lane * 4);
        ushort4 a2 = make_ushort4(0, 0, 0, 0);
        if (lane < 44) a2 = *reinterpret_cast<const ushort4*>(hp + 512 + lane * 4);
        float e[12] = {b2f(a0.x), b2f(a0.y), b2f(a0.z), b2f(a0.w),
                       b2f(a1.x), b2f(a1.y), b2f(a1.z), b2f(a1.w),
                       b2f(a2.x), b2f(a2.y), b2f(a2.z), b2f(a2.w)};
        float s = 0.f, s2 = 0.f;
#pragma unroll
        for (int k = 0; k < 12; ++k) { s += e[k]; s2 += e[k] * e[k]; }
#pragma unroll
        for (int m = 32; m; m >>= 1) { s += __shfl_xor(s, m); s2 += __shfl_xor(s2, m); }
        if (lane == 0) {
            const float mean = s * (1.f / 688.f);
            const float var  = s2 * (1.f / 688.f) - mean * mean;
            mlds[row] = mean;
            rlds[row] = rsqrtf(var + 1e-5f);
        }
    }
    __syncthreads();

    // phase 2b: normalize in place
#pragma unroll
    for (int it = 0; it < 11; ++it) {
        const int c = it * 256 + tid;
        if (c < 2752) {
            const int row = c / 86;
            const int u = c - row * 86;
            uint4 vv = *reinterpret_cast<const uint4*>(&hraw[row * 712 + u * 8]);
            const float mean = mlds[row], rstd = rlds[row];
            const ushort_t* pe = (const ushort_t*)&vv;
            ushort_t o[8];
#pragma unroll
            for (int k = 0; k < 8; ++k)
                o[k] = f2bf((b2f(pe[k]) - mean) * rstd * glds[u * 8 + k] + blds[u * 8 + k]);
            *reinterpret_cast<uint4*>(&hraw[row * 712 + u * 8]) = *reinterpret_cast<uint4*>(o);
        }
    }
    __syncthreads();

    const int rl16 = lane & 15;
    const int q4   = lane >> 4;

    // phase 3: MLP1 + gelu -> gbuf
    {
        f32x4 acc[2][2];
#pragma unroll
        for (int i = 0; i < 2; ++i) { acc[i][0] = f32x4{0,0,0,0}; acc[i][1] = f32x4{0,0,0,0}; }
        for (int kt = 0; kt < 11; ++kt) {
#pragma unroll
            for (int kk = 0; kk < 64; kk += 32) {
                bf16x8 af[2], bw[2];
#pragma unroll
                for (int n = 0; n < 2; ++n)
                    bw[n] = *reinterpret_cast<const bf16x8*>(
                        W1 + (size_t)(wv * 32 + n * 16 + rl16) * 704 + kt * 64 + kk + q4 * 8);
#pragma unroll
                for (int i = 0; i < 2; ++i)
                    af[i] = *reinterpret_cast<const bf16x8*>(
                        &hraw[(i * 16 + rl16) * 712 + kt * 64 + kk + q4 * 8]);
#pragma unroll
                for (int i = 0; i < 2; ++i)
#pragma unroll
                    for (int n = 0; n < 2; ++n)
                        acc[i][n] = __builtin_amdgcn_mfma_f32_16x16x32_bf16(
                            af[i], bw[n], acc[i][n], 0, 0, 0);
            }
        }
        const int rb = q4 * 4;
#pragma unroll
        for (int n = 0; n < 2; ++n) {
            const int col = wv * 32 + n * 16 + rl16;
            const float bc = mb1[col];
#pragma unroll
            for (int i = 0; i < 2; ++i)
#pragma unroll
                for (int r = 0; r < 4; ++r) {
                    float val = acc[i][n][r] + bc;
                    val = 0.5f * val * (1.0f + erff(val * 0.70710678118654752f));
                    gbuf[(i * 16 + rb + r) * 136 + col] = f2bf(val);
                }
        }
    }
    __syncthreads();

    // phase 4: MLP2 + final residual -> fp32 out
    for (int ch = 0; ch < 11; ++ch) {
        const int col16 = wv * 176 + ch * 16;
        if (col16 >= 688) continue;
        f32x4 acc2[2];
        acc2[0] = f32x4{0, 0, 0, 0};
        acc2[1] = f32x4{0, 0, 0, 0};
#pragma unroll
        for (int kk = 0; kk < 4; ++kk) {
            bf16x8 bw2 = *reinterpret_cast<const bf16x8*>(
                W2 + (size_t)(col16 + rl16) * 128 + kk * 32 + q4 * 8);
            bf16x8 af2[2];
#pragma unroll
            for (int i = 0; i < 2; ++i)
                af2[i] = *reinterpret_cast<const bf16x8*>(
                    &gbuf[(i * 16 + rl16) * 136 + kk * 32 + q4 * 8]);
#pragma unroll
            for (int i = 0; i < 2; ++i)
                acc2[i] = __builtin_amdgcn_mfma_f32_16x16x32_bf16(af2[i], bw2, acc2[i], 0, 0, 0);
        }
        const int col = col16 + rl16;
        const float bc = mb2[col];
#pragma unroll
        for (int i = 0; i < 2; ++i)
#pragma unroll
            for (int r = 0; r < 4; ++r) {
                const long row = r0 + i * 16 + q4 * 4 + r;
                const float raw = b2f(ovb[row * 688 + col]);
                outp[row * 688 + col] = cA * raw + cB * (acc2[i][r] + bc);
            }
    }
}

// ---------------- cross-attention (wave per row); fp8 qkv in, fp8 ctx out -------
// Dword loads (4 fp8/lane, coalesced) + hw cvt decode. Lanes 0..42 active
// (43*4 = 172 = DH_DIM).
__global__ __launch_bounds__(256)
void attn_kernel(const u8* __restrict__ qkv_v, const u8* __restrict__ qkv_i,
                 u8* __restrict__ ctx_v, u8* __restrict__ ctx_i)
{
    const int lane = threadIdx.x & 63;
    const int wave = threadIdx.x >> 6;
    const long r = (long)blockIdx.x * 4 + wave;
    const u8* bv = qkv_v + r * 2064;
    const u8* bi = qkv_i + r * 2064;
    const bool act = lane < 43;
    const int d4 = lane * 4;

    float qv[4][4], kv[4][4], vv[4][4], qi[4][4], ki[4][4], vi[4][4];
#pragma unroll
    for (int h = 0; h < 4; ++h) {
        const int o = h * DH_DIM + d4;
        unsigned int wq = act ? *reinterpret_cast<const unsigned int*>(bv + o)        : 0u;
        unsigned int wk = act ? *reinterpret_cast<const unsigned int*>(bv + 688 + o)  : 0u;
        unsigned int wv_ = act ? *reinterpret_cast<const unsigned int*>(bv + 1376 + o) : 0u;
        unsigned int xq = act ? *reinterpret_cast<const unsigned int*>(bi + o)        : 0u;
        unsigned int xk = act ? *reinterpret_cast<const unsigned int*>(bi + 688 + o)  : 0u;
        unsigned int xv = act ? *reinterpret_cast<const unsigned int*>(bi + 1376 + o) : 0u;
        dec4fp8(wq, qv[h]); dec4fp8(wk, kv[h]); dec4fp8(wv_, vv[h]);
        dec4fp8(xq, qi[h]); dec4fp8(xk, ki[h]); dec4fp8(xv, vi[h]);
    }

    float sv[4][4], si[4][4];
#pragma unroll
    for (int h = 0; h < 4; ++h)
#pragma unroll
        for (int g = 0; g < 4; ++g) {
            float a = 0.f, b = 0.f;
#pragma unroll
            for (int e = 0; e < 4; ++e) {
                a += qi[h][e] * kv[g][e];   // att_vis scores: q_ir . k_vis
                b += qv[h][e] * ki[g][e];   // att_ir  scores: q_vis . k_ir
            }
#pragma unroll
            for (int m = 32; m; m >>= 1) { a += __shfl_xor(a, m); b += __shfl_xor(b, m); }
            sv[h][g] = a; si[h][g] = b;
        }

    const float scale = 0.07624928516630235f;   // 1/sqrt(172)
    float av[4][4], ai[4][4];
#pragma unroll
    for (int h = 0; h < 4; ++h) {
        float m1 = fmaxf(fmaxf(sv[h][0], sv[h][1]), fmaxf(sv[h][2], sv[h][3])) * scale;
        float m2 = fmaxf(fmaxf(si[h][0], si[h][1]), fmaxf(si[h][2], si[h][3])) * scale;
        float d1 = 0.f, d2 = 0.f;
#pragma unroll
        for (int g = 0; g < 4; ++g) {
            av[h][g] = expf(sv[h][g] * scale - m1); d1 += av[h][g];
            ai[h][g] = expf(si[h][g] * scale - m2); d2 += ai[h][g];
        }
        const float r1 = 1.f / d1, r2 = 1.f / d2;
#pragma unroll
        for (int g = 0; g < 4; ++g) { av[h][g] *= r1; ai[h][g] *= r2; }
    }

#pragma unroll
    for (int h = 0; h < 4; ++h) {
        if (act) {
            float c0[4], c1[4];
#pragma unroll
            for (int e = 0; e < 4; ++e) {
                c0[e] = av[h][0]*vv[0][e] + av[h][1]*vv[1][e] + av[h][2]*vv[2][e] + av[h][3]*vv[3][e];
                c1[e] = ai[h][0]*vi[0][e] + ai[h][1]*vi[1][e] + ai[h][2]*vi[2][e] + ai[h][3]*vi[3][e];
            }
            *reinterpret_cast<unsigned int*>(ctx_v + r * DP + h * DH_DIM + d4) =
                pk4fp8(c0[0], c0[1], c0[2], c0[3]);
            *reinterpret_cast<unsigned int*>(ctx_i + r * DP + h * DH_DIM + d4) =
                pk4fp8(c1[0], c1[1], c1[2], c1[3]);
        }
    }
    if (lane >= 44 && lane < 48) {             // zero K-pad 688..703
        const int o = 688 + (lane - 44) * 4;
        *reinterpret_cast<unsigned int*>(ctx_v + r * DP + o) = 0u;
        *reinterpret_cast<unsigned int*>(ctx_i + r * DP + o) = 0u;
    }
}

// ---------------- host launcher ----------------
extern "C" void kernel_launch(void* const* d_in, const int* in_sizes, int n_in,
                              void* d_out, int out_size, void* d_ws, size_t ws_size,
                              hipStream_t stream)
{
    if (n_in < 35) return;
    const float* x     = (const float*)d_in[0];
    const float* x2    = (const float*)d_in[1];
    const float* Wq_v  = (const float*)d_in[2];
    const float* bq_v  = (const float*)d_in[3];
    const float* Wk_v  = (const float*)d_in[4];
    const float* bk_v  = (const float*)d_in[5];
    const float* Wv_v  = (const float*)d_in[6];
    const float* bv_v  = (const float*)d_in[7];
    const float* Wq_i  = (const float*)d_in[8];
    const float* bq_i  = (const float*)d_in[9];
    const float* Wk_i  = (const float*)d_in[10];
    const float* bk_i  = (const float*)d_in[11];
    const float* Wv_i  = (const float*)d_in[12];
    const float* bv_i  = (const float*)d_in[13];
    const float* Wo_v  = (const float*)d_in[14];
    const float* bo_v  = (const float*)d_in[15];
    const float* Wo_i  = (const float*)d_in[16];
    const float* bo_i  = (const float*)d_in[17];
    const float* ln1_g = (const float*)d_in[18];
    const float* ln1_b = (const float*)d_in[19];
    const float* ln2_g = (const float*)d_in[20];
    const float* ln2_b = (const float*)d_in[21];
    const float* ln3_g = (const float*)d_in[22];
    const float* ln3_b = (const float*)d_in[23];
    const float* ln4_g = (const float*)d_in[24];
    const float* ln4_b = (const float*)d_in[25];
    const float* m1v_W = (const float*)d_in[26];
    const float* m1v_b = (const float*)d_in[27];
    const float* m2v_W = (const float*)d_in[28];
    const float* m2v_b = (const float*)d_in[29];
    const float* m1i_W = (const float*)d_in[30];
    const float* m1i_b = (const float*)d_in[31];
    const float* m2i_W = (const float*)d_in[32];
    const float* m2i_b = (const float*)d_in[33];
    const float* coef  = (const float*)d_in[34];

    const size_t BD = (size_t)B_ROWS * D_DIM;

    char* ws = (char*)d_ws;
    size_t off = 0;
    auto give = [&](size_t bytes) {
        char* p = ws + off;
        off += (bytes + 255) & ~(size_t)255;
        return p;
    };
    u8* Wcat_v = (u8*)give(2176ull * DP);         // fp8
    u8* Wcat_i = (u8*)give(2176ull * DP);
    u8* Wo_vb  = (u8*)give(768ull * DP);
    u8* Wo_ib  = (u8*)give(768ull * DP);
    ushort_t* m1vb = (ushort_t*)give(128ull * DP * 2);   // bf16
    ushort_t* m1ib = (ushort_t*)give(128ull * DP * 2);
    ushort_t* m2vb = (ushort_t*)give(768ull * 128 * 2);
    ushort_t* m2ib = (ushort_t*)give(768ull * 128 * 2);
    float* bcat_v = (float*)give(2064 * 4);
    float* bcat_i = (float*)give(2064 * 4);
    // region X: xn fp8 (2 x B x 704 B) -> dead after QKV gemm; reused for ctx fp8
    char* regX = give((size_t)B_ROWS * DP * 2);
    // region Q: qkv fp8 (2 x B x 2064 B = 135 MB) -> dead after attn;
    // reused for bf16 ovb/oib (180 MB) -> size for the max.
    char* regQ = give(BD * 2 * 2);
    if (ws_size < off) return;

    u8* xn_v  = (u8*)regX;
    u8* xn_i  = xn_v + (size_t)B_ROWS * DP;
    u8* ctx_v = xn_v;                    // alias: xn dead after QKV gemm
    u8* ctx_i = xn_i;
    u8* qkv_v = (u8*)regQ;
    u8* qkv_i = qkv_v + (size_t)B_ROWS * 2064;
    ushort_t* ovb = (ushort_t*)regQ;     // alias: qkv dead after attn
    ushort_t* oib = ovb + BD;

    float* ov = (float*)d_out;
    float* oi = ov + BD;

    // ---- single merged weight conversion dispatch ----
    CvtJobs J;
    const float* srcs[12] = {Wq_v, Wk_v, Wv_v, Wq_i, Wk_i, Wv_i,
                             Wo_v, Wo_i, m1v_W, m1i_W, m2v_W, m2i_W};
    u8* dsts[12] = {Wcat_v, Wcat_v + 688 * DP, Wcat_v + 1376 * DP,
                    Wcat_i, Wcat_i + 688 * DP, Wcat_i + 1376 * DP,
                    Wo_vb, Wo_ib, (u8*)m1vb, (u8*)m1ib, (u8*)m2vb, (u8*)m2ib};
    int Os[12]     = {688, 688, 688, 688, 688, 688, 688, 688, 128, 128, 688, 688};
    int Opads[12]  = {688, 688, 800, 688, 688, 800, 768, 768, 128, 128, 768, 768};
    int Kins[12]   = {688, 688, 688, 688, 688, 688, 688, 688, 688, 688, 128, 128};
    int KpadBs[12] = {DP, DP, DP, DP, DP, DP, DP, DP, DP * 2, DP * 2, 256, 256};
    int fp8s[12]   = {1, 1, 1, 1, 1, 1, 1, 1, 0, 0, 0, 0};
    int bs = 0;
    for (int j = 0; j < 12; ++j) {
        J.src[j] = srcs[j]; J.dst[j] = dsts[j];
        J.O[j] = Os[j]; J.Opad[j] = Opads[j]; J.Kin[j] = Kins[j];
        J.KpadB[j] = KpadBs[j]; J.isfp8[j] = fp8s[j];
        J.bstart[j] = bs;
        bs += (Opads[j] * (KpadBs[j] >> 4) + 255) / 256;
    }
    J.bstart[12] = bs;
    cvt_all<<<dim3(bs), dim3(256), 0, stream>>>(J);

    pack_bias<<<dim3(9), dim3(256), 0, stream>>>(bq_v, bk_v, bv_v, bq_i, bk_i, bv_i,
                                                 bcat_v, bcat_i);

    // LN1 / LN2 -> xn fp8 (stride 704 B, pad zeroed)
    ln_kernel<<<dim3(2 * B_ROWS / 4), dim3(256), 0, stream>>>(
        x, x2, ln1_g, ln1_b, ln2_g, ln2_b, xn_v, xn_i);

    // QKV projections (fp8 gemmT): (B,704) @ (2176,704)^T -> (B,2064) fp8
    gemmT<0><<<dim3(128 * 17 * 2), dim3(256), 0, stream>>>(
        xn_v, xn_i, Wcat_v, Wcat_i, bcat_v, bcat_i, qkv_v, qkv_i,
        nullptr, nullptr, nullptr, 0, 0, 0, 0, 17, 2064, 704, DP, DP, 2064);

    // per-row 4x4 cross attention (fp8 in) -> ctx fp8 (stride 704 B)
    attn_kernel<<<dim3(B_ROWS / 4), dim3(256), 0, stream>>>(qkv_v, qkv_i, ctx_v, ctx_i);

    // out projections + residual (fp8 gemmT): -> bf16 out_vis/ir (stride 688)
    gemmT<1><<<dim3(128 * 6 * 2), dim3(256), 0, stream>>>(
        ctx_v, ctx_i, Wo_vb, Wo_ib, bo_v, bo_i, ovb, oib,
        x, x2, coef, 0, 1, 2, 3, 6, 688, 704, DP, DP, 688);

    // fused LN3/4 + MLP1 + gelu + MLP2 + final residual -> fp32 d_out
    mlp_fused<<<dim3(B_ROWS / 32, 2), dim3(256), 0, stream>>>(
        ovb, oib, ln3_g, ln3_b, ln4_g, ln4_b,
        m1vb, m1ib, m1v_b, m1i_b, m2vb, m2ib, m2v_b, m2i_b,
        coef, ov, oi);
}

// Round 16
// 586.515 us; speedup vs baseline: 1.0376x; 1.0376x over previous
//
#include <hip/hip_runtime.h>
#include <cmath>

// CrossKDDenseNet fused block for MI355X (gfx950).
// B=32768 rows, D=688 = 4 heads x 172, MLP hidden 128.
// FINAL (round 16 = round 14 verbatim, measured best 587.5 us):
// fp8 gemmT (b64 frag reads, counted vmcnt triple-buffer), bf16 qkv,
// wave-per-row attn, fused LN3/4+MLP1+gelu+MLP2+residual tail.

#define B_ROWS 32768
#define D_DIM  688
#define DP     704     // padded K / activation stride (fp8 bytes; 11 x 64)
#define DH_DIM 172
#define MH_DIM 128

typedef unsigned short ushort_t;
typedef unsigned char  u8;
typedef __attribute__((ext_vector_type(8))) __bf16 bf16x8;
typedef __attribute__((ext_vector_type(4))) float  f32x4;

__device__ __forceinline__ float b2f(ushort_t u) {
    return __builtin_bit_cast(float, (unsigned int)u << 16);
}
__device__ __forceinline__ ushort_t f2bf(float f) {
    unsigned int u = __builtin_bit_cast(unsigned int, f);
    u += 0x7FFFu + ((u >> 16) & 1u);   // round-to-nearest-even (finite inputs)
    return (ushort_t)(u >> 16);
}
__device__ __forceinline__ unsigned int pk4fp8(float a, float b, float c, float d) {
    int v = 0;
    v = __builtin_amdgcn_cvt_pk_fp8_f32(a, b, v, false);   // low word
    v = __builtin_amdgcn_cvt_pk_fp8_f32(c, d, v, true);    // high word
    return (unsigned int)v;
}
__device__ __forceinline__ u8 f2fp8(float a) {
    return (u8)(__builtin_amdgcn_cvt_pk_fp8_f32(a, 0.f, 0, false) & 0xff);
}

__device__ __forceinline__ void gl2lds16(const void* g, void* l) {
    __builtin_amdgcn_global_load_lds(
        (const __attribute__((address_space(1))) unsigned int*)g,
        (__attribute__((address_space(3))) unsigned int*)l, 16, 0, 0);
}

// ---------------- merged weight convert (fp8 or bf16) with zero padding ----------
struct CvtJobs {
    const float* src[12];
    u8*          dst[12];
    int O[12], Opad[12], Kin[12], KpadB[12];   // KpadB = padded row bytes
    int isfp8[12];
    int bstart[13];
};

__global__ __launch_bounds__(256)
void cvt_all(CvtJobs jobs)
{
    int b = blockIdx.x;
    int j = 0;
    while (b >= jobs.bstart[j + 1]) ++j;
    const int t = (b - jobs.bstart[j]) * 256 + threadIdx.x;
    const int KpadB = jobs.KpadB[j];
    const int Kin   = jobs.Kin[j];
    const int cpr   = KpadB >> 4;              // 16B chunks per dst row
    if (t >= jobs.Opad[j] * cpr) return;
    const int o = t / cpr;
    const int c = t - o * cpr;
    uint4 out = make_uint4(0, 0, 0, 0);
    if (jobs.isfp8[j]) {                       // 16 fp8 per chunk
        if (o < jobs.O[j] && (c * 16 + 16) <= Kin) {
            const float4* s = reinterpret_cast<const float4*>(jobs.src[j] + (size_t)o * Kin + c * 16);
            float4 f0 = s[0], f1 = s[1], f2 = s[2], f3 = s[3];
            out.x = pk4fp8(f0.x, f0.y, f0.z, f0.w);
            out.y = pk4fp8(f1.x, f1.y, f1.z, f1.w);
            out.z = pk4fp8(f2.x, f2.y, f2.z, f2.w);
            out.w = pk4fp8(f3.x, f3.y, f3.z, f3.w);
        }
    } else {                                   // 8 bf16 per chunk
        if (o < jobs.O[j] && (c * 8 + 8) <= Kin) {
            const float4* s = reinterpret_cast<const float4*>(jobs.src[j] + (size_t)o * Kin + c * 8);
            float4 f0 = s[0], f1 = s[1];
            out.x = f2bf(f0.x) | ((unsigned int)f2bf(f0.y) << 16);
            out.y = f2bf(f0.z) | ((unsigned int)f2bf(f0.w) << 16);
            out.z = f2bf(f1.x) | ((unsigned int)f2bf(f1.y) << 16);
            out.w = f2bf(f1.z) | ((unsigned int)f2bf(f1.w) << 16);
        }
    }
    *reinterpret_cast<uint4*>(jobs.dst[j] + (size_t)o * KpadB + c * 16) = out;
}

// ---------------- concat 3 biases per stream ----------------
__global__ __launch_bounds__(256)
void pack_bias(const float* __restrict__ a0, const float* __restrict__ a1,
               const float* __restrict__ a2, const float* __restrict__ b0,
               const float* __restrict__ b1, const float* __restrict__ b2,
               float* __restrict__ dv, float* __restrict__ di)
{
    int t = blockIdx.x * 256 + threadIdx.x;
    if (t >= 2064) return;
    float v, w;
    if (t < 688)       { v = a0[t];        w = b0[t]; }
    else if (t < 1376) { v = a1[t - 688];  w = b1[t - 688]; }
    else               { v = a2[t - 1376]; w = b2[t - 1376]; }
    dv[t] = v; di[t] = w;
}

// ---------------- LayerNorm fp32-in -> fp8 out; stride DP bytes, pad zeroed -----
__global__ __launch_bounds__(256)
void ln_kernel(const float* __restrict__ Xv, const float* __restrict__ Xi,
               const float* __restrict__ gv, const float* __restrict__ bv,
               const float* __restrict__ gi, const float* __restrict__ bi,
               u8* __restrict__ Yv, u8* __restrict__ Yi)
{
    const int lane = threadIdx.x & 63;
    const int wave = threadIdx.x >> 6;
    const long w = (long)blockIdx.x * 4 + wave;   // 0 .. 2B-1
    const float* X; const float* g; const float* b; u8* Y; long r;
    if (w < B_ROWS) { X = Xv; g = gv; b = bv; Y = Yv; r = w; }
    else            { X = Xi; g = gi; b = bi; Y = Yi; r = w - B_ROWS; }

    const float4* row = reinterpret_cast<const float4*>(X + r * D_DIM);
    float4 v0 = row[lane];
    float4 v1 = row[lane + 64];
    float4 v2 = make_float4(0.f, 0.f, 0.f, 0.f);
    if (lane < 44) v2 = row[lane + 128];   // 172 float4 per row

    float s  = v0.x + v0.y + v0.z + v0.w + v1.x + v1.y + v1.z + v1.w
             + v2.x + v2.y + v2.z + v2.w;
    float s2 = v0.x*v0.x + v0.y*v0.y + v0.z*v0.z + v0.w*v0.w
             + v1.x*v1.x + v1.y*v1.y + v1.z*v1.z + v1.w*v1.w
             + v2.x*v2.x + v2.y*v2.y + v2.z*v2.z + v2.w*v2.w;
#pragma unroll
    for (int m = 32; m; m >>= 1) { s += __shfl_xor(s, m); s2 += __shfl_xor(s2, m); }

    const float mean = s * (1.f / 688.f);
    const float var  = s2 * (1.f / 688.f) - mean * mean;   // biased var
    const float rstd = rsqrtf(var + 1e-5f);

    const float4* g4 = reinterpret_cast<const float4*>(g);
    const float4* b4 = reinterpret_cast<const float4*>(b);
    unsigned int* out32 = reinterpret_cast<unsigned int*>(Y + (size_t)r * DP);

    {
        float4 gg = g4[lane], bb = b4[lane];
        out32[lane] = pk4fp8((v0.x - mean) * rstd * gg.x + bb.x,
                             (v0.y - mean) * rstd * gg.y + bb.y,
                             (v0.z - mean) * rstd * gg.z + bb.z,
                             (v0.w - mean) * rstd * gg.w + bb.w);
    }
    {
        float4 gg = g4[lane + 64], bb = b4[lane + 64];
        out32[lane + 64] = pk4fp8((v1.x - mean) * rstd * gg.x + bb.x,
                                  (v1.y - mean) * rstd * gg.y + bb.y,
                                  (v1.z - mean) * rstd * gg.z + bb.z,
                                  (v1.w - mean) * rstd * gg.w + bb.w);
    }
    if (lane < 44) {
        float4 gg = g4[lane + 128], bb = b4[lane + 128];
        out32[lane + 128] = pk4fp8((v2.x - mean) * rstd * gg.x + bb.x,
                                   (v2.y - mean) * rstd * gg.y + bb.y,
                                   (v2.z - mean) * rstd * gg.z + bb.z,
                                   (v2.w - mean) * rstd * gg.w + bb.w);
    } else if (lane < 48) {
        out32[lane + 128] = 0u;            // zero K-pad 688..703
    }
}

// ================= gemmT (fp8): 256x128 tile, 4 waves x (128x64), BK=64 ========
// C(M,N) = A(M,K) @ W(N',K)^T with fp8 e4m3 operands, K=704 (11 K-tiles of 64).
// Triple-buffered 72 KB LDS (buf: A 16KB | B 8KB), one barrier per tile:
// {STAGE(t+2) | vmcnt(6) | lgkmcnt(0) | bar | 64 MFMA(t) | RD(t+1)}.
// b64 fragment reads (round-12/14 proven pattern).
// MODE 0: out bf16 = v + bias            MODE 1: out bf16 = cA*res_f32 + cB*(v+bias)
template<int MODE>
__global__ __launch_bounds__(256, 2)
void gemmT(const u8* __restrict__ A0, const u8* __restrict__ A1,
           const u8* __restrict__ W0, const u8* __restrict__ W1,
           const float* __restrict__ bias0, const float* __restrict__ bias1,
           ushort_t* __restrict__ out0, ushort_t* __restrict__ out1,
           const float* __restrict__ res0, const float* __restrict__ res1,
           const float* __restrict__ coef, int ca0, int cb0, int ca1, int cb1,
           int NBn, int N, int K, int lda, int ldw, int ldo)
{
    __shared__ __align__(16) u8 lds[73728];   // 3 bufs x 24576 B

    // bijective XCD swizzle (grid%8==0), n fastest (A-strip L2 reuse)
    const int q8 = gridDim.x >> 3;
    const int v  = (blockIdx.x & 7) * q8 + (blockIdx.x >> 3);
    const int nb = v % NBn;
    const int tmp = v / NBn;
    const int mb = tmp & 127;          // M/256 == 128
    const int zz = tmp >> 7;

    const u8* A = zz ? A1 : A0;
    const u8* W = zz ? W1 : W0;
    const float* bias = zz ? bias1 : bias0;
    ushort_t* outp    = zz ? out1 : out0;
    const float* resid = zz ? res1 : res0;
    const int ca = zz ? ca1 : ca0;
    const int cb = zz ? cb1 : cb0;

    const int tid  = threadIdx.x;
    const int lane = tid & 63;
    const int wave = tid >> 6;          // 0..3
    const int wrow = wave >> 1;         // 0..1  (128-row band)
    const int wcol = wave & 1;          // 0..1  (64-col band)
    const int m0 = mb * 256;
    const int n0 = nb * 128;
    const int rl16 = lane & 15;
    const int q4   = lane >> 4;

    const int r0a  = (wave * 64 + lane) >> 2;               // 0..63
    const int swzk = ((lane & 3) ^ ((lane >> 3) & 3)) * 16; // pre-swizzled byte col

    f32x4 acc[8][4];
#pragma unroll
    for (int i = 0; i < 8; ++i)
#pragma unroll
        for (int j = 0; j < 4; ++j)
            acc[i][j] = f32x4{0.f, 0.f, 0.f, 0.f};

    const int NT = K >> 6;              // 11

#define STAGET(kt, bb) do {                                                        \
    const u8* _a = A + (size_t)(m0 + r0a) * lda + (kt)*64 + swzk;                  \
    gl2lds16(_a,                     lds + (bb)*24576 + wave*1024);                \
    gl2lds16(_a +  64*(size_t)lda,   lds + (bb)*24576 + 4096 + wave*1024);         \
    gl2lds16(_a + 128*(size_t)lda,   lds + (bb)*24576 + 8192 + wave*1024);         \
    gl2lds16(_a + 192*(size_t)lda,   lds + (bb)*24576 + 12288 + wave*1024);        \
    const u8* _b = W + (size_t)(n0 + r0a) * ldw + (kt)*64 + swzk;                  \
    gl2lds16(_b,                     lds + (bb)*24576 + 16384 + wave*1024);        \
    gl2lds16(_b +  64*(size_t)ldw,   lds + (bb)*24576 + 20480 + wave*1024);        \
} while (0)

#define RDFRAG(bb) do {                                                            \
    _Pragma("unroll")                                                              \
    for (int kk = 0; kk < 2; ++kk) {                                               \
        const int bo = kk * 32 + q4 * 8;                                           \
        const int ch = bo >> 4, sb = bo & 15;                                      \
        _Pragma("unroll")                                                          \
        for (int i = 0; i < 8; ++i) {                                              \
            const int row_ = wrow * 128 + i * 16 + rl16;                           \
            af[kk][i] = *reinterpret_cast<const long*>(                            \
                lds + (bb) * 24576 + row_ * 64 + (((ch ^ ((row_ >> 1) & 3)) << 4) | sb)); \
        }                                                                          \
        _Pragma("unroll")                                                          \
        for (int j = 0; j < 4; ++j) {                                              \
            const int row_ = wcol * 64 + j * 16 + rl16;                            \
            bw[kk][j] = *reinterpret_cast<const long*>(                            \
                lds + (bb) * 24576 + 16384 + row_ * 64 + (((ch ^ ((row_ >> 1) & 3)) << 4) | sb)); \
        }                                                                          \
    } } while (0)

    long af[2][8], bw[2][4];

    // ---- prologue: tiles 0 and 1 in flight; read tile-0 fragments ----
    STAGET(0, 0);
    STAGET(1, 1);
    asm volatile("s_waitcnt vmcnt(6)" ::: "memory");   // tile 0 landed (own)
    __builtin_amdgcn_s_barrier();                      // all waves' tile 0 landed
    RDFRAG(0);

    for (int t = 0; t < NT; ++t) {
        const int tn2 = (t + 2 < NT) ? t + 2 : NT - 1; // clamped tail (dead bufs)
        STAGET(tn2, (t + 2) % 3);
        asm volatile("s_waitcnt vmcnt(6)" ::: "memory");    // tile t+1 landed (own)
        asm volatile("s_waitcnt lgkmcnt(0)" ::: "memory");  // my RD(t) complete
        __builtin_amdgcn_s_barrier();   // all waves: t+1 landed AND RD(t) drained
        __builtin_amdgcn_s_setprio(1);
#pragma unroll
        for (int kk = 0; kk < 2; ++kk)
#pragma unroll
            for (int i = 0; i < 8; ++i)
#pragma unroll
                for (int j = 0; j < 4; ++j)
                    acc[i][j] = __builtin_amdgcn_mfma_f32_16x16x32_fp8_fp8(
                        af[kk][i], bw[kk][j], acc[i][j], 0, 0, 0);
        __builtin_amdgcn_s_setprio(0);
        if (t + 1 < NT) RDFRAG((t + 1) % 3);   // next tile's frags
    }

    // ---- epilogue: drain all, repack C (256x128 bf16) through LDS, 16B stores --
    __syncthreads();   // vmcnt(0) + lgkmcnt(0) + barrier

    ushort_t* const Cl = reinterpret_cast<ushort_t*>(lds);   // [256][128] bf16 = 64 KB
#pragma unroll
    for (int mi = 0; mi < 8; ++mi)
#pragma unroll
        for (int nj = 0; nj < 4; ++nj)
#pragma unroll
            for (int r = 0; r < 4; ++r) {
                const int row  = wrow * 128 + mi * 16 + q4 * 4 + r;
                const int colL = wcol * 64 + nj * 16 + rl16;
                const int blk  = (colL >> 3) ^ (((row >> 2) & 3) << 1);
                Cl[row * 128 + blk * 8 + (colL & 7)] = f2bf(acc[mi][nj][r]);
            }
    __syncthreads();

    float cA = 0.f, cB = 1.f;
    if constexpr (MODE == 1) { cA = coef[ca]; cB = coef[cb]; }
#pragma unroll
    for (int it2 = 0; it2 < 16; ++it2) {
        const int c   = it2 * 256 + tid;   // 4096 chunks of 8 elems
        const int row = c >> 4;
        const int lb  = c & 15;
        const int gcol = n0 + lb * 8;
        if (gcol >= N) continue;        // N % 8 == 0
        const int pb = lb ^ (((row >> 2) & 3) << 1);
        uint4 pv = *reinterpret_cast<const uint4*>(Cl + row * 128 + pb * 8);
        const ushort_t* pu = (const ushort_t*)&pv;
        float4 b0 = *reinterpret_cast<const float4*>(bias + gcol);
        float4 b1 = *reinterpret_cast<const float4*>(bias + gcol + 4);
        const float bb[8] = {b0.x, b0.y, b0.z, b0.w, b1.x, b1.y, b1.z, b1.w};
        const size_t idx = (size_t)(m0 + row) * ldo + gcol;
        ushort_t o[8];
        if constexpr (MODE == 0) {
#pragma unroll
            for (int k = 0; k < 8; ++k) o[k] = f2bf(b2f(pu[k]) + bb[k]);
        } else {
            const float* rp = resid + idx;
            float4 r0_ = reinterpret_cast<const float4*>(rp)[0];
            float4 r1_ = reinterpret_cast<const float4*>(rp)[1];
            const float rr[8] = {r0_.x, r0_.y, r0_.z, r0_.w, r1_.x, r1_.y, r1_.z, r1_.w};
#pragma unroll
            for (int k = 0; k < 8; ++k)
                o[k] = f2bf(cA * rr[k] + cB * (b2f(pu[k]) + bb[k]));
        }
        *reinterpret_cast<uint4*>(outp + idx) = *reinterpret_cast<uint4*>(o);
    }
#undef STAGET
#undef RDFRAG
}

// ---------------- fused LN3/4 + MLP1 + gelu + MLP2 + final residual ------------
// Block = 32 rows of one stream (LDS ~60 KB -> 2 blocks/CU). bf16 path.
__global__ __launch_bounds__(256)
void mlp_fused(const ushort_t* __restrict__ ov0, const ushort_t* __restrict__ ov1,
               const float* __restrict__ g0, const float* __restrict__ b0,
               const float* __restrict__ g1, const float* __restrict__ b1,
               const ushort_t* __restrict__ W10, const ushort_t* __restrict__ W11,
               const float* __restrict__ mb10, const float* __restrict__ mb11,
               const ushort_t* __restrict__ W20, const ushort_t* __restrict__ W21,
               const float* __restrict__ mb20, const float* __restrict__ mb21,
               const float* __restrict__ coef,
               float* __restrict__ out0, float* __restrict__ out1)
{
    __shared__ __align__(16) ushort_t hraw[32 * 712];   // 45.6 KB
    __shared__ __align__(16) ushort_t gbuf[32 * 136];   // 8.7 KB
    __shared__ float glds[704];
    __shared__ float blds[704];
    __shared__ float mlds[32];
    __shared__ float rlds[32];

    const int zz = blockIdx.y;
    const ushort_t* ovb = zz ? ov1 : ov0;
    const float* lg = zz ? g1 : g0;
    const float* lb = zz ? b1 : b0;
    const ushort_t* W1 = zz ? W11 : W10;
    const float* mb1 = zz ? mb11 : mb10;
    const ushort_t* W2 = zz ? W21 : W20;
    const float* mb2 = zz ? mb21 : mb20;
    float* outp = zz ? out1 : out0;
    const float cA = coef[zz ? 6 : 4];
    const float cB = coef[zz ? 7 : 5];

    const int tid  = threadIdx.x;
    const int lane = tid & 63;
    const int wv   = tid >> 6;          // 0..3
    const long r0  = (long)blockIdx.x * 32;

    if (tid < 176) {
        float4 gg = make_float4(0, 0, 0, 0), bb = make_float4(0, 0, 0, 0);
        if (tid < 172) {
            gg = reinterpret_cast<const float4*>(lg)[tid];
            bb = reinterpret_cast<const float4*>(lb)[tid];
        }
        reinterpret_cast<float4*>(glds)[tid] = gg;
        reinterpret_cast<float4*>(blds)[tid] = bb;
    }

    // phase 1: raw rows -> LDS; cols 688..703 zeroed
#pragma unroll
    for (int it = 0; it < 11; ++it) {
        const int c = it * 256 + tid;
        const int row = c / 88;
        const int u = c - row * 88;
        uint4 vv = make_uint4(0, 0, 0, 0);
        if (u < 86)
            vv = *reinterpret_cast<const uint4*>(ovb + (r0 + row) * 688 + u * 8);
        *reinterpret_cast<uint4*>(&hraw[row * 712 + u * 8]) = vv;
    }
    __syncthreads();

    // phase 2: per-row stats
    for (int rr = 0; rr < 8; ++rr) {
        const int row = wv * 8 + rr;
        const ushort_t* hp = &hraw[row * 712];
        ushort4 a0 = *reinterpret_cast<const ushort4*>(hp + lane * 4);
        ushort4 a1 = *reinterpret_cast<const ushort4*>(hp + 256 + lane * 4);
        ushort4 a2 = make_ushort4(0, 0, 0, 0);
        if (lane < 44) a2 = *reinterpret_cast<const ushort4*>(hp + 512 + lane * 4);
        float e[12] = {b2f(a0.x), b2f(a0.y), b2f(a0.z), b2f(a0.w),
                       b2f(a1.x), b2f(a1.y), b2f(a1.z), b2f(a1.w),
                       b2f(a2.x), b2f(a2.y), b2f(a2.z), b2f(a2.w)};
        float s = 0.f, s2 = 0.f;
#pragma unroll
        for (int k = 0; k < 12; ++k) { s += e[k]; s2 += e[k] * e[k]; }
#pragma unroll
        for (int m = 32; m; m >>= 1) { s += __shfl_xor(s, m); s2 += __shfl_xor(s2, m); }
        if (lane == 0) {
            const float mean = s * (1.f / 688.f);
            const float var  = s2 * (1.f / 688.f) - mean * mean;
            mlds[row] = mean;
            rlds[row] = rsqrtf(var + 1e-5f);
        }
    }
    __syncthreads();

    // phase 2b: normalize in place
#pragma unroll
    for (int it = 0; it < 11; ++it) {
        const int c = it * 256 + tid;
        if (c < 2752) {
            const int row = c / 86;
            const int u = c - row * 86;
            uint4 vv = *reinterpret_cast<const uint4*>(&hraw[row * 712 + u * 8]);
            const float mean = mlds[row], rstd = rlds[row];
            const ushort_t* pe = (const ushort_t*)&vv;
            ushort_t o[8];
#pragma unroll
            for (int k = 0; k < 8; ++k)
                o[k] = f2bf((b2f(pe[k]) - mean) * rstd * glds[u * 8 + k] + blds[u * 8 + k]);
            *reinterpret_cast<uint4*>(&hraw[row * 712 + u * 8]) = *reinterpret_cast<uint4*>(o);
        }
    }
    __syncthreads();

    const int rl16 = lane & 15;
    const int q4   = lane >> 4;

    // phase 3: MLP1 + gelu -> gbuf
    {
        f32x4 acc[2][2];
#pragma unroll
        for (int i = 0; i < 2; ++i) { acc[i][0] = f32x4{0,0,0,0}; acc[i][1] = f32x4{0,0,0,0}; }
        for (int kt = 0; kt < 11; ++kt) {
#pragma unroll
            for (int kk = 0; kk < 64; kk += 32) {
                bf16x8 af[2], bw[2];
#pragma unroll
                for (int n = 0; n < 2; ++n)
                    bw[n] = *reinterpret_cast<const bf16x8*>(
                        W1 + (size_t)(wv * 32 + n * 16 + rl16) * 704 + kt * 64 + kk + q4 * 8);
#pragma unroll
                for (int i = 0; i < 2; ++i)
                    af[i] = *reinterpret_cast<const bf16x8*>(
                        &hraw[(i * 16 + rl16) * 712 + kt * 64 + kk + q4 * 8]);
#pragma unroll
                for (int i = 0; i < 2; ++i)
#pragma unroll
                    for (int n = 0; n < 2; ++n)
                        acc[i][n] = __builtin_amdgcn_mfma_f32_16x16x32_bf16(
                            af[i], bw[n], acc[i][n], 0, 0, 0);
            }
        }
        const int rb = q4 * 4;
#pragma unroll
        for (int n = 0; n < 2; ++n) {
            const int col = wv * 32 + n * 16 + rl16;
            const float bc = mb1[col];
#pragma unroll
            for (int i = 0; i < 2; ++i)
#pragma unroll
                for (int r = 0; r < 4; ++r) {
                    float val = acc[i][n][r] + bc;
                    val = 0.5f * val * (1.0f + erff(val * 0.70710678118654752f));
                    gbuf[(i * 16 + rb + r) * 136 + col] = f2bf(val);
                }
        }
    }
    __syncthreads();

    // phase 4: MLP2 + final residual -> fp32 out
    for (int ch = 0; ch < 11; ++ch) {
        const int col16 = wv * 176 + ch * 16;
        if (col16 >= 688) continue;
        f32x4 acc2[2];
        acc2[0] = f32x4{0, 0, 0, 0};
        acc2[1] = f32x4{0, 0, 0, 0};
#pragma unroll
        for (int kk = 0; kk < 4; ++kk) {
            bf16x8 bw2 = *reinterpret_cast<const bf16x8*>(
                W2 + (size_t)(col16 + rl16) * 128 + kk * 32 + q4 * 8);
            bf16x8 af2[2];
#pragma unroll
            for (int i = 0; i < 2; ++i)
                af2[i] = *reinterpret_cast<const bf16x8*>(
                    &gbuf[(i * 16 + rl16) * 136 + kk * 32 + q4 * 8]);
#pragma unroll
            for (int i = 0; i < 2; ++i)
                acc2[i] = __builtin_amdgcn_mfma_f32_16x16x32_bf16(af2[i], bw2, acc2[i], 0, 0, 0);
        }
        const int col = col16 + rl16;
        const float bc = mb2[col];
#pragma unroll
        for (int i = 0; i < 2; ++i)
#pragma unroll
            for (int r = 0; r < 4; ++r) {
                const long row = r0 + i * 16 + q4 * 4 + r;
                const float raw = b2f(ovb[row * 688 + col]);
                outp[row * 688 + col] = cA * raw + cB * (acc2[i][r] + bc);
            }
    }
}

// ---------------- cross-attention (wave per row); bf16 qkv in, fp8 ctx out ------
__global__ __launch_bounds__(256)
void attn_kernel(const ushort_t* __restrict__ qkv_v, const ushort_t* __restrict__ qkv_i,
                 u8* __restrict__ ctx_v, u8* __restrict__ ctx_i)
{
    const int lane = threadIdx.x & 63;
    const int wave = threadIdx.x >> 6;
    const long r = (long)blockIdx.x * 4 + wave;
    const ushort_t* bv = qkv_v + r * 2064;
    const ushort_t* bi = qkv_i + r * 2064;

    float sv[4][4], si[4][4];
#pragma unroll
    for (int h = 0; h < 4; ++h)
#pragma unroll
        for (int g = 0; g < 4; ++g) { sv[h][g] = 0.f; si[h][g] = 0.f; }

    float vvr[3][4], vir[3][4];
#pragma unroll
    for (int it = 0; it < 3; ++it) {
        const int d = lane + it * 64;
        const bool ok = d < DH_DIM;
        float qv[4], kv[4], qi[4], ki[4];
#pragma unroll
        for (int h = 0; h < 4; ++h) {
            const int o = h * DH_DIM + d;
            qv[h]      = ok ? b2f(bv[o]) : 0.f;
            kv[h]      = ok ? b2f(bv[D_DIM + o]) : 0.f;
            vvr[it][h] = ok ? b2f(bv[2 * D_DIM + o]) : 0.f;
            qi[h]      = ok ? b2f(bi[o]) : 0.f;
            ki[h]      = ok ? b2f(bi[D_DIM + o]) : 0.f;
            vir[it][h] = ok ? b2f(bi[2 * D_DIM + o]) : 0.f;
        }
#pragma unroll
        for (int h = 0; h < 4; ++h)
#pragma unroll
            for (int g = 0; g < 4; ++g) {
                sv[h][g] += qi[h] * kv[g];   // att_vis scores: q_ir . k_vis
                si[h][g] += qv[h] * ki[g];   // att_ir  scores: q_vis . k_ir
            }
    }

#pragma unroll
    for (int h = 0; h < 4; ++h)
#pragma unroll
        for (int g = 0; g < 4; ++g) {
            float a = sv[h][g], b = si[h][g];
#pragma unroll
            for (int m = 32; m; m >>= 1) { a += __shfl_xor(a, m); b += __shfl_xor(b, m); }
            sv[h][g] = a; si[h][g] = b;
        }

    const float scale = 0.07624928516630235f;   // 1/sqrt(172)
    float av[4][4], ai[4][4];
#pragma unroll
    for (int h = 0; h < 4; ++h) {
        float m1 = fmaxf(fmaxf(sv[h][0], sv[h][1]), fmaxf(sv[h][2], sv[h][3])) * scale;
        float m2 = fmaxf(fmaxf(si[h][0], si[h][1]), fmaxf(si[h][2], si[h][3])) * scale;
        float d1 = 0.f, d2 = 0.f;
#pragma unroll
        for (int g = 0; g < 4; ++g) {
            av[h][g] = expf(sv[h][g] * scale - m1); d1 += av[h][g];
            ai[h][g] = expf(si[h][g] * scale - m2); d2 += ai[h][g];
        }
        const float r1 = 1.f / d1, r2 = 1.f / d2;
#pragma unroll
        for (int g = 0; g < 4; ++g) { av[h][g] *= r1; ai[h][g] *= r2; }
    }

#pragma unroll
    for (int it = 0; it < 3; ++it) {
        const int d = lane + it * 64;
        if (d < DH_DIM) {
#pragma unroll
            for (int h = 0; h < 4; ++h) {
                float cv = av[h][0] * vvr[it][0] + av[h][1] * vvr[it][1]
                         + av[h][2] * vvr[it][2] + av[h][3] * vvr[it][3];
                float ci = ai[h][0] * vir[it][0] + ai[h][1] * vir[it][1]
                         + ai[h][2] * vir[it][2] + ai[h][3] * vir[it][3];
                ctx_v[r * DP + h * DH_DIM + d] = f2fp8(cv);
                ctx_i[r * DP + h * DH_DIM + d] = f2fp8(ci);
            }
        }
    }
    if (lane < 16) {                       // zero K-pad 688..703
        ctx_v[r * DP + 688 + lane] = 0;
        ctx_i[r * DP + 688 + lane] = 0;
    }
}

// ---------------- host launcher ----------------
extern "C" void kernel_launch(void* const* d_in, const int* in_sizes, int n_in,
                              void* d_out, int out_size, void* d_ws, size_t ws_size,
                              hipStream_t stream)
{
    if (n_in < 35) return;
    const float* x     = (const float*)d_in[0];
    const float* x2    = (const float*)d_in[1];
    const float* Wq_v  = (const float*)d_in[2];
    const float* bq_v  = (const float*)d_in[3];
    const float* Wk_v  = (const float*)d_in[4];
    const float* bk_v  = (const float*)d_in[5];
    const float* Wv_v  = (const float*)d_in[6];
    const float* bv_v  = (const float*)d_in[7];
    const float* Wq_i  = (const float*)d_in[8];
    const float* bq_i  = (const float*)d_in[9];
    const float* Wk_i  = (const float*)d_in[10];
    const float* bk_i  = (const float*)d_in[11];
    const float* Wv_i  = (const float*)d_in[12];
    const float* bv_i  = (const float*)d_in[13];
    const float* Wo_v  = (const float*)d_in[14];
    const float* bo_v  = (const float*)d_in[15];
    const float* Wo_i  = (const float*)d_in[16];
    const float* bo_i  = (const float*)d_in[17];
    const float* ln1_g = (const float*)d_in[18];
    const float* ln1_b = (const float*)d_in[19];
    const float* ln2_g = (const float*)d_in[20];
    const float* ln2_b = (const float*)d_in[21];
    const float* ln3_g = (const float*)d_in[22];
    const float* ln3_b = (const float*)d_in[23];
    const float* ln4_g = (const float*)d_in[24];
    const float* ln4_b = (const float*)d_in[25];
    const float* m1v_W = (const float*)d_in[26];
    const float* m1v_b = (const float*)d_in[27];
    const float* m2v_W = (const float*)d_in[28];
    const float* m2v_b = (const float*)d_in[29];
    const float* m1i_W = (const float*)d_in[30];
    const float* m1i_b = (const float*)d_in[31];
    const float* m2i_W = (const float*)d_in[32];
    const float* m2i_b = (const float*)d_in[33];
    const float* coef  = (const float*)d_in[34];

    const size_t BD = (size_t)B_ROWS * D_DIM;

    char* ws = (char*)d_ws;
    size_t off = 0;
    auto give = [&](size_t bytes) {
        char* p = ws + off;
        off += (bytes + 255) & ~(size_t)255;
        return p;
    };
    u8* Wcat_v = (u8*)give(2176ull * DP);         // fp8
    u8* Wcat_i = (u8*)give(2176ull * DP);
    u8* Wo_vb  = (u8*)give(768ull * DP);
    u8* Wo_ib  = (u8*)give(768ull * DP);
    ushort_t* m1vb = (ushort_t*)give(128ull * DP * 2);   // bf16
    ushort_t* m1ib = (ushort_t*)give(128ull * DP * 2);
    ushort_t* m2vb = (ushort_t*)give(768ull * 128 * 2);
    ushort_t* m2ib = (ushort_t*)give(768ull * 128 * 2);
    float* bcat_v = (float*)give(2064 * 4);
    float* bcat_i = (float*)give(2064 * 4);
    // region X: xn fp8 (2 x B x 704 B) -> dead after QKV gemm; reused for ctx fp8
    char* regX = give((size_t)B_ROWS * DP * 2);
    // region Q: qkv bf16 (2 x B x 2064) -> dead after attn; reused for bf16 ovb/oib
    char* regQ = give((size_t)B_ROWS * 2064 * 2 * 2);
    if (ws_size < off) return;

    u8* xn_v  = (u8*)regX;
    u8* xn_i  = xn_v + (size_t)B_ROWS * DP;
    u8* ctx_v = xn_v;                    // alias: xn dead after QKV gemm
    u8* ctx_i = xn_i;
    ushort_t* qkv_v = (ushort_t*)regQ;
    ushort_t* qkv_i = qkv_v + (size_t)B_ROWS * 2064;
    ushort_t* ovb   = (ushort_t*)regQ;   // alias: qkv dead after attn
    ushort_t* oib   = ovb + BD;

    float* ov = (float*)d_out;
    float* oi = ov + BD;

    // ---- single merged weight conversion dispatch ----
    CvtJobs J;
    const float* srcs[12] = {Wq_v, Wk_v, Wv_v, Wq_i, Wk_i, Wv_i,
                             Wo_v, Wo_i, m1v_W, m1i_W, m2v_W, m2i_W};
    u8* dsts[12] = {Wcat_v, Wcat_v + 688 * DP, Wcat_v + 1376 * DP,
                    Wcat_i, Wcat_i + 688 * DP, Wcat_i + 1376 * DP,
                    Wo_vb, Wo_ib, (u8*)m1vb, (u8*)m1ib, (u8*)m2vb, (u8*)m2ib};
    int Os[12]     = {688, 688, 688, 688, 688, 688, 688, 688, 128, 128, 688, 688};
    int Opads[12]  = {688, 688, 800, 688, 688, 800, 768, 768, 128, 128, 768, 768};
    int Kins[12]   = {688, 688, 688, 688, 688, 688, 688, 688, 688, 688, 128, 128};
    int KpadBs[12] = {DP, DP, DP, DP, DP, DP, DP, DP, DP * 2, DP * 2, 256, 256};
    int fp8s[12]   = {1, 1, 1, 1, 1, 1, 1, 1, 0, 0, 0, 0};
    int bs = 0;
    for (int j = 0; j < 12; ++j) {
        J.src[j] = srcs[j]; J.dst[j] = dsts[j];
        J.O[j] = Os[j]; J.Opad[j] = Opads[j]; J.Kin[j] = Kins[j];
        J.KpadB[j] = KpadBs[j]; J.isfp8[j] = fp8s[j];
        J.bstart[j] = bs;
        bs += (Opads[j] * (KpadBs[j] >> 4) + 255) / 256;
    }
    J.bstart[12] = bs;
    cvt_all<<<dim3(bs), dim3(256), 0, stream>>>(J);

    pack_bias<<<dim3(9), dim3(256), 0, stream>>>(bq_v, bk_v, bv_v, bq_i, bk_i, bv_i,
                                                 bcat_v, bcat_i);

    // LN1 / LN2 -> xn fp8 (stride 704 B, pad zeroed)
    ln_kernel<<<dim3(2 * B_ROWS / 4), dim3(256), 0, stream>>>(
        x, x2, ln1_g, ln1_b, ln2_g, ln2_b, xn_v, xn_i);

    // QKV projections (fp8 gemmT): (B,704) @ (2176,704)^T -> (B,2064) bf16
    gemmT<0><<<dim3(128 * 17 * 2), dim3(256), 0, stream>>>(
        xn_v, xn_i, Wcat_v, Wcat_i, bcat_v, bcat_i, qkv_v, qkv_i,
        nullptr, nullptr, nullptr, 0, 0, 0, 0, 17, 2064, 704, DP, DP, 2064);

    // per-row 4x4 cross attention -> ctx fp8 (stride 704 B)
    attn_kernel<<<dim3(B_ROWS / 4), dim3(256), 0, stream>>>(qkv_v, qkv_i, ctx_v, ctx_i);

    // out projections + residual (fp8 gemmT): -> bf16 out_vis/ir (stride 688)
    gemmT<1><<<dim3(128 * 6 * 2), dim3(256), 0, stream>>>(
        ctx_v, ctx_i, Wo_vb, Wo_ib, bo_v, bo_i, ovb, oib,
        x, x2, coef, 0, 1, 2, 3, 6, 688, 704, DP, DP, 688);

    // fused LN3/4 + MLP1 + gelu + MLP2 + final residual -> fp32 d_out
    mlp_fused<<<dim3(B_ROWS / 32, 2), dim3(256), 0, stream>>>(
        ovb, oib, ln3_g, ln3_b, ln4_g, ln4_b,
        m1vb, m1ib, m1v_b, m1i_b, m2vb, m2ib, m2v_b, m2i_b,
        coef, ov, oi);
}